// Round 2
// baseline (268.873 us; speedup 1.0000x reference)
//
#include <hip/hip_runtime.h>

constexpr int FRAME_LEN = 130;   // floats per frame
constexpr int HALF      = 65;    // floats per hand block
constexpr int BLOCK     = 256;   // threads per block
constexpr int FPB       = 32;    // frames per block
constexpr int CHUNK_F   = FPB * FRAME_LEN;   // 4160 floats per block

// 4-byte-aligned float4: gfx950 global loads support dword-aligned dwordx4
// (unaligned-access mode), so this can stay a single global_load_dwordx4.
typedef float f4u __attribute__((ext_vector_type(4), aligned(4)));

// frame = idx / 130 for idx < 7825 via magic multiply (8067 = ceil(2^20/130))
__device__ __forceinline__ int div130(int idx) {
    return (int)(((unsigned)idx * 8067u) >> 20);
}

__global__ __launch_bounds__(BLOCK, 8)   // 8 blocks/CU, 100% occupancy
void hand_sorter_kernel(const float* __restrict__ X, float* __restrict__ out,
                        int n_frames) {
    // Only per-frame source offsets live in LDS: 0 (skip) or +65 (swap).
    __shared__ int s_off[FPB];

    const int t = threadIdx.x;
    const long long frame0 = (long long)blockIdx.x * FPB;
    const long long rem = (long long)n_frames - frame0;
    const int frames_here = rem < (long long)FPB ? (int)rem : FPB;
    const int nf = frames_here * FRAME_LEN;       // floats in this chunk
    const int n4 = (nf + 3) >> 2;                 // float4 slots (1040 full chunk)
    const long long base = frame0 * (long long)FRAME_LEN;
    const float* __restrict__ Xb = X + base;
    float* __restrict__ Ob = out + base;

    // ---- Phase 1: per-frame skip predicate from tiny header reads ----
    if (t < frames_here) {
        const float* fr = Xb + t * FRAME_LEN;
        const float h0 = fr[0];
        const float p0 = fr[1];
        const float h1 = fr[HALF];
        const float p1 = fr[HALF + 1];
        const bool nan0 = (h0 != h0);
        const bool nan1 = (h1 != h1);
        const bool no_nan = !nan0 && !nan1;
        const bool eq = (h0 == h1);
        const bool skip =
            (h1 > h0) ||
            (nan0 && nan1) ||
            (nan0 && (h1 == 1.0f)) ||
            (nan1 && (h0 == 0.0f)) ||
            (no_nan && eq && (h0 == 0.0f) && (p0 > p1)) ||
            (no_nan && eq && (h0 == 1.0f) && (p0 < p1));
        s_off[t] = skip ? 0 : HALF;
    }
    __syncthreads();

    // ---- Phase 2: global->global stream, no data staging ----
    // out[idx] = X[frame*130 + ((jj + off) mod 130)], off in {0, 65}.
    // Source runs are contiguous except where a vec4 straddles the half
    // boundary (jj in {62,63,64}) or a frame boundary (jj > 126).
    for (int i = t; i < n4; i += BLOCK) {
        const int idx = 4 * i;
        const int fl = div130(idx);
        const int jj = idx - fl * FRAME_LEN;
        const bool same_frame = (idx + 3 < nf) && (jj <= FRAME_LEN - 4);
        const bool no_half_cross = (jj < HALF - 3) || (jj >= HALF);
        if (same_frame && no_half_cross) {
            int sj = jj + s_off[fl];
            if (sj >= FRAME_LEN) sj -= FRAME_LEN;
            const float* src = Xb + (fl * FRAME_LEN + sj);
            f4u v = *(const f4u*)src;
            float4 o;
            o.x = v.x; o.y = v.y; o.z = v.z; o.w = v.w;
            *(float4*)(Ob + idx) = o;            // 16B-aligned coalesced store
        } else {
            // boundary-straddling vec4 (~2 per frame) or partial tail
#pragma unroll
            for (int e = 0; e < 4; ++e) {
                const int ide = idx + e;
                if (ide < nf) {
                    const int fle = div130(ide);
                    const int je = ide - fle * FRAME_LEN;
                    int sj = je + s_off[fle];
                    if (sj >= FRAME_LEN) sj -= FRAME_LEN;
                    Ob[ide] = Xb[fle * FRAME_LEN + sj];
                }
            }
        }
    }
}

extern "C" void kernel_launch(void* const* d_in, const int* in_sizes, int n_in,
                              void* d_out, int out_size, void* d_ws, size_t ws_size,
                              hipStream_t stream) {
    const float* X = (const float*)d_in[0];
    float* out = (float*)d_out;
    const int n_frames = in_sizes[0] / FRAME_LEN;   // 262144
    const int n_blocks = (n_frames + FPB - 1) / FPB;
    hand_sorter_kernel<<<n_blocks, BLOCK, 0, stream>>>(X, out, n_frames);
}

// Round 3
// 237.539 us; speedup vs baseline: 1.1319x; 1.1319x over previous
//
#include <hip/hip_runtime.h>

constexpr int FRAME_LEN = 130;   // floats per frame
constexpr int HALF      = 65;    // floats per hand block
constexpr int BLOCK     = 256;   // threads per block
constexpr int FPB       = 32;    // frames per block
constexpr int CHUNK_F   = FPB * FRAME_LEN;   // 4160 floats
constexpr int N4        = CHUNK_F / 4;       // 1040 vec4 = 4*256 + 16

// frame = idx / 130 for idx < 7825 via magic multiply
__device__ __forceinline__ int div130(int idx) {
    return (int)(((unsigned)idx * 8067u) >> 20);
}

__device__ __forceinline__ bool skip_pred(float h0, float p0, float h1, float p1) {
    const bool nan0 = (h0 != h0);
    const bool nan1 = (h1 != h1);
    const bool no_nan = !nan0 && !nan1;
    const bool eq = (h0 == h1);
    return (h1 > h0) ||
           (nan0 && nan1) ||
           (nan0 && (h1 == 1.0f)) ||
           (nan1 && (h0 == 0.0f)) ||
           (no_nan && eq && (h0 == 0.0f) && (p0 > p1)) ||
           (no_nan && eq && (h0 == 1.0f) && (p0 < p1));
}

__global__ __launch_bounds__(BLOCK, 8)   // 8 blocks/CU, 100% occupancy
void hand_sorter_kernel(const float* __restrict__ X, float* __restrict__ out,
                        int n_frames) {
    __shared__ float s_buf[CHUNK_F];
    __shared__ unsigned s_mask;          // bit f set => frame f skips (no swap)

    const int t = threadIdx.x;
    const long long frame0 = (long long)blockIdx.x * FPB;
    const long long rem = (long long)n_frames - frame0;
    const int frames_here = rem < (long long)FPB ? (int)rem : FPB;
    const long long base = frame0 * (long long)FRAME_LEN;
    const float* __restrict__ Xb = X + base;
    float* __restrict__ Ob = out + base;

    if (frames_here == FPB) {
        // ================= fast path: full 32-frame chunk =================
        const float4* __restrict__ Xv = (const float4*)Xb;
        float4* __restrict__ Ov = (float4*)Ob;

        // ---- staging loads: 4(+1) independent dwordx4 in flight ----
        float4 r0 = Xv[t];
        float4 r1 = Xv[t + 256];
        float4 r2 = Xv[t + 512];
        float4 r3 = Xv[t + 768];
        float4 r4;
        if (t < 16) r4 = Xv[t + 1024];

        // ---- concurrent header loads -> skip bitmask (wave 0 only) ----
        bool skip = false;
        if (t < FPB) {
            const float* fr = Xb + t * FRAME_LEN;
            skip = skip_pred(fr[0], fr[1], fr[HALF], fr[HALF + 1]);
        }
        if (t < 64) {
            unsigned long long b = __ballot(skip);
            if (t == 0) s_mask = (unsigned)b;
        }

        // ---- LDS writes ----
        *(float4*)(s_buf + 4 * t)         = r0;
        *(float4*)(s_buf + 4 * (t + 256)) = r1;
        *(float4*)(s_buf + 4 * (t + 512)) = r2;
        *(float4*)(s_buf + 4 * (t + 768)) = r3;
        if (t < 16) *(float4*)(s_buf + 4 * (t + 1024)) = r4;
        __syncthreads();

        const unsigned mask = s_mask;

        // ---- gather: 4(+1) outputs/thread, fully unrolled ----
        float4 o[4];
#pragma unroll
        for (int k = 0; k < 4; ++k) {
            const int idx = 4 * (t + k * 256);
            float* op = (float*)&o[k];
#pragma unroll
            for (int e = 0; e < 4; ++e) {
                const int ide = idx + e;
                const int fle = div130(ide);
                const int je  = ide - fle * FRAME_LEN;
                int sj = je + (((mask >> fle) & 1u) ? 0 : HALF);
                if (sj >= FRAME_LEN) sj -= FRAME_LEN;
                op[e] = s_buf[fle * FRAME_LEN + sj];
            }
        }
        float4 o4;
        if (t < 16) {
            const int idx = 4 * (t + 1024);
            float* op = (float*)&o4;
#pragma unroll
            for (int e = 0; e < 4; ++e) {
                const int ide = idx + e;
                const int fle = div130(ide);
                const int je  = ide - fle * FRAME_LEN;
                int sj = je + (((mask >> fle) & 1u) ? 0 : HALF);
                if (sj >= FRAME_LEN) sj -= FRAME_LEN;
                op[e] = s_buf[fle * FRAME_LEN + sj];
            }
        }

        // ---- aligned coalesced stores ----
#pragma unroll
        for (int k = 0; k < 4; ++k) Ov[t + k * 256] = o[k];
        if (t < 16) Ov[t + 1024] = o4;
    } else {
        // ================= generic tail path (never taken for bench shape) ====
        const int nf = frames_here * FRAME_LEN;
        for (int i = t; i < nf; i += BLOCK) {
            const int fle = div130(i);
            const int je  = i - fle * FRAME_LEN;
            const float* fr = Xb + fle * FRAME_LEN;
            const bool skip = skip_pred(fr[0], fr[1], fr[HALF], fr[HALF + 1]);
            int sj = je + (skip ? 0 : HALF);
            if (sj >= FRAME_LEN) sj -= FRAME_LEN;
            Ob[i] = fr[sj];
        }
    }
}

extern "C" void kernel_launch(void* const* d_in, const int* in_sizes, int n_in,
                              void* d_out, int out_size, void* d_ws, size_t ws_size,
                              hipStream_t stream) {
    const float* X = (const float*)d_in[0];
    float* out = (float*)d_out;
    const int n_frames = in_sizes[0] / FRAME_LEN;   // 262144
    const int n_blocks = (n_frames + FPB - 1) / FPB;
    hand_sorter_kernel<<<n_blocks, BLOCK, 0, stream>>>(X, out, n_frames);
}